// Round 1
// baseline (98.997 us; speedup 1.0000x reference)
//
#include <hip/hip_runtime.h>

// DepthOffset: for each (b, tap j, oy, ox) find argmin_k |sample(j,k) - center|
// sample(j,k) at (oy + 4*(jr-1) + 2*(kr-1), ox + 4*(jc-1) + 2*(kc-1))
// with TWO-stage zero padding:
//   stage 1 (Sp pad, PH=4): tap pos (oy+4*(jr-1), ox+4*(jc-1)) must be in-bounds else 0
//   stage 2 (dp pad, SD=2): final pos must be in-bounds else 0
// masks: taps j=1,7 allow only kc==1; taps j=3,5 allow only kr==1.
// out[b, j,    oy, ox] = (kbest/3 - 1)*2   (off_h)
// out[b, 9+j,  oy, ox] = (kbest%3 - 1)*2   (off_w)

#define BATCH 4
#define IH 480
#define IW 640

__global__ __launch_bounds__(256) void depth_offset_kernel(
    const float* __restrict__ d, int* __restrict__ out) {
  int idx = blockIdx.x * blockDim.x + threadIdx.x;
  if (idx >= BATCH * IH * IW) return;
  int ox = idx % IW;
  int t = idx / IW;
  int oy = t % IH;
  int b = t / IH;

  const float* __restrict__ db = d + (size_t)b * (IH * IW);
  float center = db[oy * IW + ox];

  // 7x7 neighborhood at even offsets -6..+6; nb[i][jj] corresponds to
  // (oy + 2*i - 6, ox + 2*jj - 6); zero outside image (stage-2 pad).
  float nb[7][7];
#pragma unroll
  for (int i = 0; i < 7; ++i) {
    int y = oy + 2 * i - 6;
    bool yok = ((unsigned)y < (unsigned)IH);
#pragma unroll
    for (int jj = 0; jj < 7; ++jj) {
      int x = ox + 2 * jj - 6;
      float v = 0.0f;
      if (yok && ((unsigned)x < (unsigned)IW)) v = db[y * IW + x];
      nb[i][jj] = v;
    }
  }

  const size_t plane = (size_t)IH * IW;
  int* __restrict__ outb = out + (size_t)b * 18 * plane;
  size_t pix = (size_t)oy * IW + ox;

#pragma unroll
  for (int j = 0; j < 9; ++j) {
    const int jr = j / 3, jc = j % 3;
    // stage-1 (tap-level) bounds check
    int Y = oy + 4 * (jr - 1);
    int X = ox + 4 * (jc - 1);
    bool jok = ((unsigned)Y < (unsigned)IH) && ((unsigned)X < (unsigned)IW);

    float best = __builtin_huge_valf();
    int bk = 0;
#pragma unroll
    for (int k = 0; k < 9; ++k) {
      const int kr = k / 3, kc = k % 3;
      // masking: j in {1,7} -> only kc==1; j in {3,5} -> only kr==1
      bool allowed = true;
      if (j == 1 || j == 7) allowed = (kc == 1);
      if (j == 3 || j == 5) allowed = (kr == 1);
      if (!allowed) continue;  // masked entries are +inf, never the argmin

      float v = jok ? nb[2 * jr + kr][2 * jc + kc] : 0.0f;
      float diff = fabsf(v - center);
      if (diff < best) {  // strict <: first minimum wins (matches jnp.argmin)
        best = diff;
        bk = k;
      }
    }
    outb[(size_t)j * plane + pix] = (bk / 3 - 1) * 2;
    outb[(size_t)(9 + j) * plane + pix] = (bk % 3 - 1) * 2;
  }
}

extern "C" void kernel_launch(void* const* d_in, const int* in_sizes, int n_in,
                              void* d_out, int out_size, void* d_ws, size_t ws_size,
                              hipStream_t stream) {
  const float* depth = (const float*)d_in[0];
  int* out = (int*)d_out;
  const int total = BATCH * IH * IW;
  const int block = 256;
  const int grid = (total + block - 1) / block;
  depth_offset_kernel<<<grid, block, 0, stream>>>(depth, out);
}